// Round 6
// baseline (372.826 us; speedup 1.0000x reference)
//
#include <hip/hip_runtime.h>
#include <cstdint>

// Problem constants
#define Bn   32
#define Cn   256
#define Hn   56
#define Wn   56
#define HWn  (Hn*Wn)           // 3136
#define NPIX (Bn*HWn)          // 100352
#define WELEMS (Cn*Cn*9)       // 589824
#define EPSv 1e-5f

// padded channels-last activation plane: [b][58 rows][58 cols][256 ci] i8
// per-pixel 256B block stored XOR-swizzled: 16B slot s lives at s ^ (padded_col & 15)
#define PR   58
#define PPLANE (PR*PR)         // 3364

// ws layout (bytes)
#define F_WABS  0              // float index
#define F_SUM   64             // float[256]
#define F_SQ    320            // float[256]
#define STATS_BYTES 4096
#define WPK_OFF  4096                     // i8 wpk[kc=36][co=256][64]  (A repack)
#define WPK_BYTES WELEMS                  // 589824
#define ACT_OFF  (WPK_OFF + WPK_BYTES)    // 593920 (16B aligned)
#define ACT_BYTES (Bn*PPLANE*Cn)          // 27553792

typedef int v4i __attribute__((ext_vector_type(4)));

// ---------------------------------------------------------------------------
// Fused packing kernel (unchanged — verified rounds 3-5).
__global__ void pack_all(const float* __restrict__ x,
                         const float* __restrict__ w,
                         float* __restrict__ wsf,
                         uint8_t* __restrict__ wpk,
                         uint8_t* __restrict__ act) {
    if (blockIdx.x < 392) {
        int v = blockIdx.x * 256 + threadIdx.x;   // 0..100351
        // --- halo zeroing: 32 batches * 228 border pixels = 7296 ---
        if (v < 7296) {
            int b = v / 228;
            int r = v - b * 228;
            int y, xx;
            if (r < 58)       { y = 0;  xx = r; }
            else if (r < 116) { y = 57; xx = r - 58; }
            else { int r2 = r - 116; y = 1 + (r2 >> 1); xx = (r2 & 1) * 57; }
            uint4* d = (uint4*)(act + ((size_t)(b * PR + y) * PR + xx) * 256);
            uint4 z = make_uint4(0, 0, 0, 0);
            #pragma unroll
            for (int i = 0; i < 16; i++) d[i] = z;
        }
        // --- interior pack with per-pixel XOR swizzle ---
        int b = v / HWn;
        int p = v - b * HWn;
        int y = p / Wn;
        int xx = p - y * Wn;
        const float* xp = x + (size_t)b * Cn * HWn + p;
        int key = (xx + 1) & 15;
        uint32_t* dst = (uint32_t*)(act + ((size_t)(b * PR + (y + 1)) * PR + (xx + 1)) * 256);
        #pragma unroll
        for (int slot = 0; slot < 16; slot++) {
            uint32_t rr[4];
            #pragma unroll
            for (int cw = 0; cw < 4; cw++) {
                uint32_t r = 0;
                #pragma unroll
                for (int j = 0; j < 4; j++) {
                    uint32_t sgn = __float_as_uint(xp[(size_t)(slot * 16 + cw * 4 + j) * HWn]) >> 31;
                    r |= (sgn ? 0xFFu : 0x01u) << (j * 8);
                }
                rr[cw] = r;
            }
            *(uint4*)(dst + (size_t)((slot ^ key) * 4)) = make_uint4(rr[0], rr[1], rr[2], rr[3]);
        }
    } else {
        int u = (blockIdx.x - 392) * 256 + threadIdx.x;   // 36*256 = 9216
        int co = u / 36;
        int kc = u - co * 36;
        int t  = kc >> 2;          // tap
        int s  = kc & 3;           // 64-ci chunk
        const float* wp = w + (size_t)co * 2304 + t;      // OIHW
        uint32_t* dst = (uint32_t*)(wpk + ((size_t)kc * 256 + co) * 64);
        float sabs = 0.0f;
        #pragma unroll
        for (int cw = 0; cw < 16; cw++) {
            uint32_t r = 0;
            #pragma unroll
            for (int j = 0; j < 4; j++) {
                int ci = s * 64 + cw * 4 + j;
                float wv = wp[(size_t)ci * 9];
                sabs += fminf(fabsf(wv), 1.0f);
                r |= ((__float_as_uint(wv) >> 31) ? 0xFFu : 0x01u) << (j * 8);
            }
            dst[cw] = r;
        }
        #pragma unroll
        for (int off = 32; off; off >>= 1) sabs += __shfl_down(sabs, off);
        __shared__ float sh[4];
        if ((threadIdx.x & 63) == 0) sh[threadIdx.x >> 6] = sabs;
        __syncthreads();
        if (threadIdx.x == 0)
            atomicAdd(&wsf[F_WABS], sh[0] + sh[1] + sh[2] + sh[3]);
    }
}

// ---------------------------------------------------------------------------
// Binary conv as implicit GEMM on the i8 matrix pipe, LDS-staged B.
// Round-6: OCCUPANCY version. 8 waves / 512 threads per block; wave tile
// 32co x 112px (2 M-frags x 7 N-frags) -> acc 56 regs; single-buffer bf (28)
// + single-buffer af (8, distance-1) + tap-walk state (14) ~= 115 unified
// regs <= 128 => __launch_bounds__(512,4): 2 blocks/CU = 16 waves = 4/SIMD
// (vs 2/SIMD in rounds 2-5, where MfmaUtil was pinned at ~17%).
// Latency hiding now comes from TLP (4 waves/SIMD), not fragile source ILP.
__global__ __launch_bounds__(512, 4) void conv_mfma(
    const uint8_t* __restrict__ act, const uint8_t* __restrict__ wpk,
    const float* __restrict__ x, float* __restrict__ wsf,
    float* __restrict__ out) {
    __shared__ uint4 ldsv[3712];              // 59392 B
    uint8_t* lds = (uint8_t*)ldsv;

    const int tid  = threadIdx.x;
    const int lane = tid & 63;
    const int wid  = tid >> 6;                // 0..7
    const int l15  = lane & 15;
    const int l4   = lane >> 4;               // 0..3

    const int bx = blockIdx.x;                // 0..895
    const int b  = bx / 28;
    const int y0 = (bx - b * 28) * 2;         // first output image row

    // Stage padded rows y0..y0+3 = one contiguous 59392B block of act.
    {
        const uint4* src = (const uint4*)(act + ((size_t)b * PR + y0) * PR * 256);
        for (int i = tid; i < 3712; i += 512) ldsv[i] = src[i];
    }

    // A-fragment lane base (co = wid*32 + mi*16 + l15, bytes l4*16)
    const uint8_t* abase = wpk + (wid * 32 + l15) * 64 + l4 * 16;

    // A prologue: single buffer, distance-1; fill with kc = 0.
    v4i af[2];
    #pragma unroll
    for (int mi = 0; mi < 2; mi++)
        af[mi] = *(const v4i*)(abase + mi * 1024);

    // Tap-walking state for t=0 (dh=-1, dw=-1): window corner (r_, c_) local.
    int pixb[7], key[7];
    #pragma unroll
    for (int ni = 0; ni < 7; ni++) {
        int n  = ni * 16 + l15;
        int r_ = n / 56;
        int c_ = n - r_ * 56;
        pixb[ni] = (r_ * 58 + c_) * 256;
        key[ni]  = c_ & 15;
    }

    __syncthreads();

    v4i acc[2][7] = {};

// STEP: load bf for sub-step S, run 14 MFMAs on resident af, then reload af
// with the NEXT K-chunk (distance-1; consumption is one SIMD-round away,
// ~1000+ cyc at 4 waves/SIMD, >> L2 latency).
#define STEP(S, KCN)                                                           \
    {                                                                          \
        v4i bf[7];                                                             \
        _Pragma("unroll")                                                      \
        for (int ni = 0; ni < 7; ni++)                                         \
            bf[ni] = *(const v4i*)(lds + pixb[ni] +                            \
                                   ((((S) * 4 + l4) ^ key[ni]) << 4));         \
        _Pragma("unroll")                                                      \
        for (int ni = 0; ni < 7; ni++) {                                       \
            _Pragma("unroll")                                                  \
            for (int mi = 0; mi < 2; mi++)                                     \
                acc[mi][ni] = __builtin_amdgcn_mfma_i32_16x16x64_i8(           \
                    af[mi], bf[ni], acc[mi][ni], 0, 0, 0);                     \
        }                                                                      \
        {                                                                      \
            int kcn = (KCN) > 35 ? 35 : (KCN);                                 \
            const uint8_t* ap = abase + (size_t)kcn * 16384;                   \
            _Pragma("unroll")                                                  \
            for (int mi = 0; mi < 2; mi++)                                     \
                af[mi] = *(const v4i*)(ap + mi * 1024);                        \
        }                                                                      \
    }

    #pragma unroll 1
    for (int t = 0; t < 9; t++) {
        const int t4 = t * 4;
        STEP(0, t4 + 1)
        STEP(1, t4 + 2)
        STEP(2, t4 + 3)
        STEP(3, t4 + 4)
        // Tap-walk t -> t+1: dw cycles -1,0,1 (ddw=+1, dtoff=+256), wrapping
        // at t=2,5 (ddw=-2, dtoff=(58-2)*256); t=8 is the end (no-op).
        const int wrap  = (t == 2 || t == 5);
        const int dtoff = (t == 8) ? 0 : (wrap ? 56 * 256 : 256);
        const int ddw   = (t == 8) ? 0 : (wrap ? -2 : 1);
        #pragma unroll
        for (int ni = 0; ni < 7; ni++) {
            pixb[ni] += dtoff;
            key[ni]   = (key[ni] + ddw) & 15;
        }
    }
#undef STEP

    const float mv = wsf[F_WABS] * (1.0f / (float)WELEMS);
    const int co_w = wid * 32;
    const int pbase = b * (Cn * HWn) + y0 * 56;

    // Epilogue: scale + shortcut + store + per-channel partial stats.
    float ssum[2][4] = {}, ssq[2][4] = {};
    #pragma unroll
    for (int mi = 0; mi < 2; mi++) {
        #pragma unroll
        for (int ni = 0; ni < 7; ni++) {
            v4i a = acc[mi][ni];
            #pragma unroll
            for (int q = 0; q < 4; q++) {
                int co = co_w + mi * 16 + l4 * 4 + q;
                size_t idx = (size_t)pbase + (size_t)co * HWn + (ni * 16 + l15);
                float val = fmaf(mv, (float)a[q], x[idx]);
                out[idx] = val;
                ssum[mi][q] += val;
                ssq[mi][q]  += val * val;
            }
        }
    }
    // Reduce across the 16 lanes (l15) sharing each channel, then atomics.
    #pragma unroll
    for (int mi = 0; mi < 2; mi++) {
        #pragma unroll
        for (int q = 0; q < 4; q++) {
            float s = ssum[mi][q], sq = ssq[mi][q];
            #pragma unroll
            for (int off = 1; off < 16; off <<= 1) {
                s  += __shfl_xor(s, off);
                sq += __shfl_xor(sq, off);
            }
            if (l15 == 0) {
                int co = co_w + mi * 16 + l4 * 4 + q;
                atomicAdd(&wsf[F_SUM + co], s);
                atomicAdd(&wsf[F_SQ  + co], sq);
            }
        }
    }
}

// ---------------------------------------------------------------------------
// BN finalize (per-plane, from fused stats) + normalize + ReLU, in place.
__global__ void epilogue_kernel(float* __restrict__ out,
                                const float* __restrict__ wsf,
                                const float* __restrict__ g,
                                const float* __restrict__ bt) {
    int plane = blockIdx.x;   // b*256 + c
    int c = plane & 255;
    const float n = (float)(Bn * HWn);
    float mean = wsf[F_SUM + c] / n;
    float var  = wsf[F_SQ + c] / n - mean * mean;
    float sc = g[c] * rsqrtf(var + EPSv);
    float sh = bt[c] - mean * sc;
    float4* o4 = (float4*)(out + (size_t)plane * HWn);
    for (int i = threadIdx.x; i < HWn / 4; i += 256) {
        float4 v = o4[i];
        v.x = fmaxf(fmaf(v.x, sc, sh), 0.0f);
        v.y = fmaxf(fmaf(v.y, sc, sh), 0.0f);
        v.z = fmaxf(fmaf(v.z, sc, sh), 0.0f);
        v.w = fmaxf(fmaf(v.w, sc, sh), 0.0f);
        o4[i] = v;
    }
}

// ---------------------------------------------------------------------------
extern "C" void kernel_launch(void* const* d_in, const int* in_sizes, int n_in,
                              void* d_out, int out_size, void* d_ws, size_t ws_size,
                              hipStream_t stream) {
    const float* x     = (const float*)d_in[0];
    const float* w     = (const float*)d_in[1];
    const float* gamma = (const float*)d_in[2];
    const float* beta  = (const float*)d_in[3];
    float* out = (float*)d_out;

    float*   wsf = (float*)d_ws;
    uint8_t* wpk = (uint8_t*)d_ws + WPK_OFF;
    uint8_t* act = (uint8_t*)d_ws + ACT_OFF;

    hipMemsetAsync(d_ws, 0, STATS_BYTES, stream);
    pack_all<<<dim3(428), dim3(256), 0, stream>>>(x, w, wsf, wpk, act);
    conv_mfma<<<dim3(896), dim3(512), 0, stream>>>(act, wpk, x, wsf, out);
    epilogue_kernel<<<dim3(Bn * Cn), dim3(256), 0, stream>>>(out, wsf, gamma, beta);
}

// Round 7
// 364.253 us; speedup vs baseline: 1.0235x; 1.0235x over previous
//
#include <hip/hip_runtime.h>
#include <cstdint>

// Problem constants
#define Bn   32
#define Cn   256
#define Hn   56
#define Wn   56
#define HWn  (Hn*Wn)           // 3136
#define NPIX (Bn*HWn)          // 100352
#define WELEMS (Cn*Cn*9)       // 589824
#define EPSv 1e-5f

// padded channels-last activation plane: [b][58 rows][58 cols][256 ci] fp8
// per-pixel 256B block stored XOR-swizzled: 16B slot s lives at s ^ (padded_col & 15)
#define PR   58
#define PPLANE (PR*PR)         // 3364

// fp8 e4m3 (OCP) encodings of +1 / -1; padding 0x00 = +0.0 contributes nothing.
#define FP8_P1 0x38u
#define FP8_M1 0xB8u

// ws layout (bytes)
#define F_WABS  0              // float index
#define F_SUM   64             // float[256]
#define F_SQ    320            // float[256]
#define STATS_BYTES 4096
#define WPK_OFF  4096                     // fp8 wpk[kc=36][co=256][64]  (A repack)
#define WPK_BYTES WELEMS                  // 589824
#define ACT_OFF  (WPK_OFF + WPK_BYTES)    // 593920 (16B aligned)
#define ACT_BYTES (Bn*PPLANE*Cn)          // 27553792

typedef float v4f __attribute__((ext_vector_type(4)));
typedef long  v2l __attribute__((ext_vector_type(2)));

// ---------------------------------------------------------------------------
// Fused packing kernel (structure verified rounds 3-6; values now fp8 ±1).
__global__ void pack_all(const float* __restrict__ x,
                         const float* __restrict__ w,
                         float* __restrict__ wsf,
                         uint8_t* __restrict__ wpk,
                         uint8_t* __restrict__ act) {
    if (blockIdx.x < 392) {
        int v = blockIdx.x * 256 + threadIdx.x;   // 0..100351
        // --- halo zeroing: 32 batches * 228 border pixels = 7296 ---
        if (v < 7296) {
            int b = v / 228;
            int r = v - b * 228;
            int y, xx;
            if (r < 58)       { y = 0;  xx = r; }
            else if (r < 116) { y = 57; xx = r - 58; }
            else { int r2 = r - 116; y = 1 + (r2 >> 1); xx = (r2 & 1) * 57; }
            uint4* d = (uint4*)(act + ((size_t)(b * PR + y) * PR + xx) * 256);
            uint4 z = make_uint4(0, 0, 0, 0);
            #pragma unroll
            for (int i = 0; i < 16; i++) d[i] = z;
        }
        // --- interior pack with per-pixel XOR swizzle ---
        int b = v / HWn;
        int p = v - b * HWn;
        int y = p / Wn;
        int xx = p - y * Wn;
        const float* xp = x + (size_t)b * Cn * HWn + p;
        int key = (xx + 1) & 15;
        uint32_t* dst = (uint32_t*)(act + ((size_t)(b * PR + (y + 1)) * PR + (xx + 1)) * 256);
        #pragma unroll
        for (int slot = 0; slot < 16; slot++) {
            uint32_t rr[4];
            #pragma unroll
            for (int cw = 0; cw < 4; cw++) {
                uint32_t r = 0;
                #pragma unroll
                for (int j = 0; j < 4; j++) {
                    uint32_t sgn = __float_as_uint(xp[(size_t)(slot * 16 + cw * 4 + j) * HWn]) >> 31;
                    r |= (sgn ? FP8_M1 : FP8_P1) << (j * 8);
                }
                rr[cw] = r;
            }
            *(uint4*)(dst + (size_t)((slot ^ key) * 4)) = make_uint4(rr[0], rr[1], rr[2], rr[3]);
        }
    } else {
        int u = (blockIdx.x - 392) * 256 + threadIdx.x;   // 36*256 = 9216
        int co = u / 36;
        int kc = u - co * 36;
        int t  = kc >> 2;          // tap
        int s  = kc & 3;           // 64-ci chunk
        const float* wp = w + (size_t)co * 2304 + t;      // OIHW
        uint32_t* dst = (uint32_t*)(wpk + ((size_t)kc * 256 + co) * 64);
        float sabs = 0.0f;
        #pragma unroll
        for (int cw = 0; cw < 16; cw++) {
            uint32_t r = 0;
            #pragma unroll
            for (int j = 0; j < 4; j++) {
                int ci = s * 64 + cw * 4 + j;
                float wv = wp[(size_t)ci * 9];
                sabs += fminf(fabsf(wv), 1.0f);
                r |= ((__float_as_uint(wv) >> 31) ? FP8_M1 : FP8_P1) << (j * 8);
            }
            dst[cw] = r;
        }
        #pragma unroll
        for (int off = 32; off; off >>= 1) sabs += __shfl_down(sabs, off);
        __shared__ float sh[4];
        if ((threadIdx.x & 63) == 0) sh[threadIdx.x >> 6] = sabs;
        __syncthreads();
        if (threadIdx.x == 0)
            atomicAdd(&wsf[F_WABS], sh[0] + sh[1] + sh[2] + sh[3]);
    }
}

// ---------------------------------------------------------------------------
// Binary conv as implicit GEMM, fp8 e4m3 on the matrix pipe (LDS-staged B).
// Geometry/schedule = round-4 (best measured): 4 waves, wave tile 64co x
// 112px, 4-deep A-pipeline (af0..af3, distance 4 K-chunks), single bf,
// runtime t-loop with incremental tap walk.
// Change vs round-4: mfma_i32_16x16x64_i8 -> 2x mfma_f32_16x16x32_fp8_fp8
// (each 16B fragment = two K=32 halves). fp8 runs at the HW-verified bf16
// MFMA rate; the i8 shape is suspected ~4x off its spec rate (the ~120us
// floor invariant across rounds 2-6). +-1 products accumulate exactly in f32
// -> numerics identical.
__global__ __launch_bounds__(256, 2) void conv_mfma(
    const uint8_t* __restrict__ act, const uint8_t* __restrict__ wpk,
    const float* __restrict__ x, float* __restrict__ wsf,
    float* __restrict__ out) {
    __shared__ uint4 ldsv[3712];              // 59392 B
    uint8_t* lds = (uint8_t*)ldsv;

    const int tid  = threadIdx.x;
    const int lane = tid & 63;
    const int wid  = tid >> 6;                // 0..3
    const int l15  = lane & 15;
    const int l4   = lane >> 4;               // 0..3

    const int bx = blockIdx.x;                // 0..895
    const int b  = bx / 28;
    const int y0 = (bx - b * 28) * 2;         // first output image row

    // Stage padded rows y0..y0+3 = one contiguous 59392B block of act.
    {
        const uint4* src = (const uint4*)(act + ((size_t)b * PR + y0) * PR * 256);
        for (int i = tid; i < 3712; i += 256) ldsv[i] = src[i];
    }

    // A-fragment lane base (co = wid*64 + mi*16 + l15, bytes l4*16)
    const uint8_t* abase = wpk + (wid * 64 + l15) * 64 + l4 * 16;

    // Pipeline prologue: fill the 4 A-buffers with kc = 0..3.
    v2l af0[4], af1[4], af2[4], af3[4];
    #pragma unroll
    for (int mi = 0; mi < 4; mi++) {
        af0[mi] = *(const v2l*)(abase + (size_t)0 * 16384 + mi * 1024);
        af1[mi] = *(const v2l*)(abase + (size_t)1 * 16384 + mi * 1024);
        af2[mi] = *(const v2l*)(abase + (size_t)2 * 16384 + mi * 1024);
        af3[mi] = *(const v2l*)(abase + (size_t)3 * 16384 + mi * 1024);
    }

    // Tap-walking state for t=0 (dh=-1, dw=-1): window corner (r_, c_) local.
    int pixb[7], key[7];
    #pragma unroll
    for (int ni = 0; ni < 7; ni++) {
        int n  = ni * 16 + l15;
        int r_ = n / 56;
        int c_ = n - r_ * 56;
        pixb[ni] = (r_ * 58 + c_) * 256;
        key[ni]  = c_ & 15;
    }

    __syncthreads();

    v4f acc[4][7] = {};

// STEP: load bf for sub-step S (16B = two K=32 fp8 fragments), run 2x28 MFMA
// on the resident AF buffer, then reload AF with K-chunk KCN (distance-4).
#define STEP(S, AF)                                                            \
    {                                                                          \
        v2l bf[7];                                                             \
        _Pragma("unroll")                                                      \
        for (int ni = 0; ni < 7; ni++)                                         \
            bf[ni] = *(const v2l*)(lds + pixb[ni] +                            \
                                   ((((S) * 4 + l4) ^ key[ni]) << 4));         \
        _Pragma("unroll")                                                      \
        for (int ni = 0; ni < 7; ni++) {                                       \
            _Pragma("unroll")                                                  \
            for (int mi = 0; mi < 4; mi++) {                                   \
                acc[mi][ni] = __builtin_amdgcn_mfma_f32_16x16x32_fp8_fp8(      \
                    AF[mi][0], bf[ni][0], acc[mi][ni], 0, 0, 0);               \
                acc[mi][ni] = __builtin_amdgcn_mfma_f32_16x16x32_fp8_fp8(      \
                    AF[mi][1], bf[ni][1], acc[mi][ni], 0, 0, 0);               \
            }                                                                  \
        }                                                                      \
        {                                                                      \
            int kcn = t4 + (S) + 4;                                            \
            kcn = kcn > 35 ? 35 : kcn;   /* tail: redundant reload, unused */  \
            const uint8_t* ap = abase + (size_t)kcn * 16384;                   \
            _Pragma("unroll")                                                  \
            for (int mi = 0; mi < 4; mi++)                                     \
                AF[mi] = *(const v2l*)(ap + mi * 1024);                        \
        }                                                                      \
    }

    #pragma unroll 1
    for (int t = 0; t < 9; t++) {
        const int t4 = t * 4;
        STEP(0, af0)
        STEP(1, af1)
        STEP(2, af2)
        STEP(3, af3)
        // Tap-walk t -> t+1: dw cycles -1,0,1 (ddw=+1, dtoff=+256), wrapping
        // at t=2,5 (ddw=-2, dtoff=(58-2)*256); t=8 is the end (no-op).
        const int wrap  = (t == 2 || t == 5);
        const int dtoff = (t == 8) ? 0 : (wrap ? 56 * 256 : 256);
        const int ddw   = (t == 8) ? 0 : (wrap ? -2 : 1);
        #pragma unroll
        for (int ni = 0; ni < 7; ni++) {
            pixb[ni] += dtoff;
            key[ni]   = (key[ni] + ddw) & 15;
        }
    }
#undef STEP

    const float mv = wsf[F_WABS] * (1.0f / (float)WELEMS);
    const int co_w = wid * 64;
    const int pbase = b * (Cn * HWn) + y0 * 56;

    // Epilogue: scale + shortcut + store + per-channel partial stats.
    float ssum[4][4] = {}, ssq[4][4] = {};
    #pragma unroll
    for (int mi = 0; mi < 4; mi++) {
        #pragma unroll
        for (int ni = 0; ni < 7; ni++) {
            v4f a = acc[mi][ni];
            #pragma unroll
            for (int q = 0; q < 4; q++) {
                int co = co_w + mi * 16 + l4 * 4 + q;
                size_t idx = (size_t)pbase + (size_t)co * HWn + (ni * 16 + l15);
                float val = fmaf(mv, a[q], x[idx]);
                out[idx] = val;
                ssum[mi][q] += val;
                ssq[mi][q]  += val * val;
            }
        }
    }
    // Reduce across the 16 lanes (l15) sharing each channel, then atomics.
    #pragma unroll
    for (int mi = 0; mi < 4; mi++) {
        #pragma unroll
        for (int q = 0; q < 4; q++) {
            float s = ssum[mi][q], sq = ssq[mi][q];
            #pragma unroll
            for (int off = 1; off < 16; off <<= 1) {
                s  += __shfl_xor(s, off);
                sq += __shfl_xor(sq, off);
            }
            if (l15 == 0) {
                int co = co_w + mi * 16 + l4 * 4 + q;
                atomicAdd(&wsf[F_SUM + co], s);
                atomicAdd(&wsf[F_SQ  + co], sq);
            }
        }
    }
}

// ---------------------------------------------------------------------------
// BN finalize (per-plane, from fused stats) + normalize + ReLU, in place.
__global__ void epilogue_kernel(float* __restrict__ out,
                                const float* __restrict__ wsf,
                                const float* __restrict__ g,
                                const float* __restrict__ bt) {
    int plane = blockIdx.x;   // b*256 + c
    int c = plane & 255;
    const float n = (float)(Bn * HWn);
    float mean = wsf[F_SUM + c] / n;
    float var  = wsf[F_SQ + c] / n - mean * mean;
    float sc = g[c] * rsqrtf(var + EPSv);
    float sh = bt[c] - mean * sc;
    float4* o4 = (float4*)(out + (size_t)plane * HWn);
    for (int i = threadIdx.x; i < HWn / 4; i += 256) {
        float4 v = o4[i];
        v.x = fmaxf(fmaf(v.x, sc, sh), 0.0f);
        v.y = fmaxf(fmaf(v.y, sc, sh), 0.0f);
        v.z = fmaxf(fmaf(v.z, sc, sh), 0.0f);
        v.w = fmaxf(fmaf(v.w, sc, sh), 0.0f);
        o4[i] = v;
    }
}

// ---------------------------------------------------------------------------
extern "C" void kernel_launch(void* const* d_in, const int* in_sizes, int n_in,
                              void* d_out, int out_size, void* d_ws, size_t ws_size,
                              hipStream_t stream) {
    const float* x     = (const float*)d_in[0];
    const float* w     = (const float*)d_in[1];
    const float* gamma = (const float*)d_in[2];
    const float* beta  = (const float*)d_in[3];
    float* out = (float*)d_out;

    float*   wsf = (float*)d_ws;
    uint8_t* wpk = (uint8_t*)d_ws + WPK_OFF;
    uint8_t* act = (uint8_t*)d_ws + ACT_OFF;

    hipMemsetAsync(d_ws, 0, STATS_BYTES, stream);
    pack_all<<<dim3(428), dim3(256), 0, stream>>>(x, w, wsf, wpk, act);
    conv_mfma<<<dim3(896), dim3(256), 0, stream>>>(act, wpk, x, wsf, out);
    epilogue_kernel<<<dim3(Bn * Cn), dim3(256), 0, stream>>>(out, wsf, gamma, beta);
}

// Round 8
// 345.993 us; speedup vs baseline: 1.0776x; 1.0528x over previous
//
#include <hip/hip_runtime.h>
#include <cstdint>

// Problem constants
#define Bn   32
#define Cn   256
#define Hn   56
#define Wn   56
#define HWn  (Hn*Wn)           // 3136
#define NPIX (Bn*HWn)          // 100352
#define WELEMS (Cn*Cn*9)       // 589824
#define EPSv 1e-5f

// padded channels-last activation plane: [b][58 rows][58 cols][256 ci] i8
// per-pixel 256B block stored XOR-swizzled: 16B slot s lives at s ^ (padded_col & 15)
#define PR   58
#define PPLANE (PR*PR)         // 3364

// ws layout (floats for wsf): [8..43] = 36 per-block |w| partials (plain
// stores, no init needed); [64..319] = F_SUM; [320..575] = F_SQ (zeroed by
// pack_all blocks 0/1, which complete before conv via stream ordering).
#define F_WPART 8
#define F_SUM   64
#define F_SQ    320
#define WPK_OFF  4096                     // i8 wpk[kc=36][co=256][64]  (A repack)
#define WPK_BYTES WELEMS                  // 589824
#define ACT_OFF  (WPK_OFF + WPK_BYTES)    // 593920 (16B aligned)
#define ACT_BYTES (Bn*PPLANE*Cn)          // 27553792

typedef int v4i __attribute__((ext_vector_type(4)));

#define GLOBAL_AS __attribute__((address_space(1)))
#define LDS_AS    __attribute__((address_space(3)))

// ---------------------------------------------------------------------------
// Fused packing kernel. Activation blocks 0..391 (+ blocks 0/1 zero the BN
// stats accumulators); weight blocks 392..427 store per-block |w| partials.
__global__ void pack_all(const float* __restrict__ x,
                         const float* __restrict__ w,
                         float* __restrict__ wsf,
                         uint8_t* __restrict__ wpk,
                         uint8_t* __restrict__ act) {
    if (blockIdx.x < 392) {
        // --- BN-stats zero-init (replaces the memset dispatch) ---
        if (blockIdx.x < 2)
            wsf[F_SUM + blockIdx.x * 256 + threadIdx.x] = 0.0f;

        int v = blockIdx.x * 256 + threadIdx.x;   // 0..100351
        // --- halo zeroing: 32 batches * 228 border pixels = 7296 ---
        if (v < 7296) {
            int b = v / 228;
            int r = v - b * 228;
            int y, xx;
            if (r < 58)       { y = 0;  xx = r; }
            else if (r < 116) { y = 57; xx = r - 58; }
            else { int r2 = r - 116; y = 1 + (r2 >> 1); xx = (r2 & 1) * 57; }
            uint4* d = (uint4*)(act + ((size_t)(b * PR + y) * PR + xx) * 256);
            uint4 z = make_uint4(0, 0, 0, 0);
            #pragma unroll
            for (int i = 0; i < 16; i++) d[i] = z;
        }
        // --- interior pack with per-pixel XOR swizzle ---
        int b = v / HWn;
        int p = v - b * HWn;
        int y = p / Wn;
        int xx = p - y * Wn;
        const float* xp = x + (size_t)b * Cn * HWn + p;
        int key = (xx + 1) & 15;
        uint32_t* dst = (uint32_t*)(act + ((size_t)(b * PR + (y + 1)) * PR + (xx + 1)) * 256);
        #pragma unroll
        for (int slot = 0; slot < 16; slot++) {
            uint32_t rr[4];
            #pragma unroll
            for (int cw = 0; cw < 4; cw++) {
                uint32_t r = 0;
                #pragma unroll
                for (int j = 0; j < 4; j++) {
                    uint32_t sgn = __float_as_uint(xp[(size_t)(slot * 16 + cw * 4 + j) * HWn]) >> 31;
                    r |= (sgn ? 0xFFu : 0x01u) << (j * 8);
                }
                rr[cw] = r;
            }
            *(uint4*)(dst + (size_t)((slot ^ key) * 4)) = make_uint4(rr[0], rr[1], rr[2], rr[3]);
        }
    } else {
        int u = (blockIdx.x - 392) * 256 + threadIdx.x;   // 36*256 = 9216
        int co = u / 36;
        int kc = u - co * 36;
        int t  = kc >> 2;          // tap
        int s  = kc & 3;           // 64-ci chunk
        const float* wp = w + (size_t)co * 2304 + t;      // OIHW
        uint32_t* dst = (uint32_t*)(wpk + ((size_t)kc * 256 + co) * 64);
        float sabs = 0.0f;
        #pragma unroll
        for (int cw = 0; cw < 16; cw++) {
            uint32_t r = 0;
            #pragma unroll
            for (int j = 0; j < 4; j++) {
                int ci = s * 64 + cw * 4 + j;
                float wv = wp[(size_t)ci * 9];
                sabs += fminf(fabsf(wv), 1.0f);
                r |= ((__float_as_uint(wv) >> 31) ? 0xFFu : 0x01u) << (j * 8);
            }
            dst[cw] = r;
        }
        #pragma unroll
        for (int off = 32; off; off >>= 1) sabs += __shfl_down(sabs, off);
        __shared__ float sh[4];
        if ((threadIdx.x & 63) == 0) sh[threadIdx.x >> 6] = sabs;
        __syncthreads();
        if (threadIdx.x == 0)   // plain store: no atomic, no init required
            wsf[F_WPART + (blockIdx.x - 392)] = sh[0] + sh[1] + sh[2] + sh[3];
    }
}

// ---------------------------------------------------------------------------
// Binary conv as implicit GEMM on the i8 matrix pipe, LDS-staged B.
// Compute structure = round-4 (best measured: 4 waves, wave tile 64co x
// 112px, depth-4 A-pipeline af0..af3, single bf, runtime t-loop).
// Round-8 change: staging via global_load_lds (async DMA, linear LDS dest,
// per-lane global src) instead of the serialized load->wait->ds_write loop
// that exposed ~14K cycles of HBM latency per block behind one barrier.
__global__ __launch_bounds__(256, 2) void conv_mfma(
    const uint8_t* __restrict__ act, const uint8_t* __restrict__ wpk,
    const float* __restrict__ x, float* __restrict__ wsf,
    float* __restrict__ out) {
    __shared__ uint4 ldsv[3712];              // 59392 B = 58 chunks of 1KB
    uint8_t* lds = (uint8_t*)ldsv;

    const int tid  = threadIdx.x;
    const int lane = tid & 63;
    const int wid  = tid >> 6;                // 0..3
    const int l15  = lane & 15;
    const int l4   = lane >> 4;               // 0..3

    const int bx = blockIdx.x;                // 0..895
    const int b  = bx / 28;
    const int y0 = (bx - b * 28) * 2;         // first output image row

    // Stage padded rows y0..y0+3 via async global->LDS DMA: 58 x 1KB chunks,
    // wave w issues chunks {w, w+4, ...} back-to-back, no waits here.
    {
        const uint8_t* src = act + ((size_t)b * PR + y0) * PR * 256;
        #pragma unroll
        for (int j = 0; j < 15; j++) {
            int c = wid + j * 4;               // wave-uniform
            if (c < 58) {
                __builtin_amdgcn_global_load_lds(
                    (const GLOBAL_AS uint32_t*)(const void*)(src + c * 1024 + lane * 16),
                    (LDS_AS uint32_t*)(void*)(lds + c * 1024),
                    16, 0, 0);
            }
        }
    }

    // A-fragment lane base (co = wid*64 + mi*16 + l15, bytes l4*16)
    const uint8_t* abase = wpk + (wid * 64 + l15) * 64 + l4 * 16;

    // Pipeline prologue: fill the 4 A-buffers with kc = 0..3.
    v4i af0[4], af1[4], af2[4], af3[4];
    #pragma unroll
    for (int mi = 0; mi < 4; mi++) {
        af0[mi] = *(const v4i*)(abase + (size_t)0 * 16384 + mi * 1024);
        af1[mi] = *(const v4i*)(abase + (size_t)1 * 16384 + mi * 1024);
        af2[mi] = *(const v4i*)(abase + (size_t)2 * 16384 + mi * 1024);
        af3[mi] = *(const v4i*)(abase + (size_t)3 * 16384 + mi * 1024);
    }

    // Tap-walking state for t=0 (dh=-1, dw=-1): window corner (r_, c_) local.
    int pixb[7], key[7];
    #pragma unroll
    for (int ni = 0; ni < 7; ni++) {
        int n  = ni * 16 + l15;
        int r_ = n / 56;
        int c_ = n - r_ * 56;
        pixb[ni] = (r_ * 58 + c_) * 256;
        key[ni]  = c_ & 15;
    }

    __syncthreads();   // drains vmcnt(0): LDS-DMA chunks + af loads all ready

    v4i acc[4][7] = {};

// STEP: load bf for sub-step S, run 28 MFMAs on the resident AF buffer,
// then reload AF with K-chunk KCN (distance-4 ahead, clamped tail).
#define STEP(S, AF)                                                            \
    {                                                                          \
        v4i bf[7];                                                             \
        _Pragma("unroll")                                                      \
        for (int ni = 0; ni < 7; ni++)                                         \
            bf[ni] = *(const v4i*)(lds + pixb[ni] +                            \
                                   ((((S) * 4 + l4) ^ key[ni]) << 4));         \
        _Pragma("unroll")                                                      \
        for (int ni = 0; ni < 7; ni++) {                                       \
            _Pragma("unroll")                                                  \
            for (int mi = 0; mi < 4; mi++)                                     \
                acc[mi][ni] = __builtin_amdgcn_mfma_i32_16x16x64_i8(           \
                    AF[mi], bf[ni], acc[mi][ni], 0, 0, 0);                     \
        }                                                                      \
        {                                                                      \
            int kcn = t4 + (S) + 4;                                            \
            kcn = kcn > 35 ? 35 : kcn;   /* tail: redundant reload, unused */  \
            const uint8_t* ap = abase + (size_t)kcn * 16384;                   \
            _Pragma("unroll")                                                  \
            for (int mi = 0; mi < 4; mi++)                                     \
                AF[mi] = *(const v4i*)(ap + mi * 1024);                        \
        }                                                                      \
    }

    #pragma unroll 1
    for (int t = 0; t < 9; t++) {
        const int t4 = t * 4;
        STEP(0, af0)
        STEP(1, af1)
        STEP(2, af2)
        STEP(3, af3)
        // Tap-walk t -> t+1: dw cycles -1,0,1 (ddw=+1, dtoff=+256), wrapping
        // at t=2,5 (ddw=-2, dtoff=(58-2)*256); t=8 is the end (no-op).
        const int wrap  = (t == 2 || t == 5);
        const int dtoff = (t == 8) ? 0 : (wrap ? 56 * 256 : 256);
        const int ddw   = (t == 8) ? 0 : (wrap ? -2 : 1);
        #pragma unroll
        for (int ni = 0; ni < 7; ni++) {
            pixb[ni] += dtoff;
            key[ni]   = (key[ni] + ddw) & 15;
        }
    }
#undef STEP

    // mean(|clip(w)|) from the 36 per-block partials (uniform, cheap).
    float wabs = 0.0f;
    #pragma unroll
    for (int j = 0; j < 36; j++) wabs += wsf[F_WPART + j];
    const float mv = wabs * (1.0f / (float)WELEMS);

    const int co_w = wid * 64;
    const int pbase = b * (Cn * HWn) + y0 * 56;

    // Epilogue: scale + shortcut + store + per-channel partial stats.
    float ssum[4][4] = {}, ssq[4][4] = {};
    #pragma unroll
    for (int mi = 0; mi < 4; mi++) {
        #pragma unroll
        for (int ni = 0; ni < 7; ni++) {
            v4i a = acc[mi][ni];
            #pragma unroll
            for (int q = 0; q < 4; q++) {
                int co = co_w + mi * 16 + l4 * 4 + q;
                size_t idx = (size_t)pbase + (size_t)co * HWn + (ni * 16 + l15);
                float val = fmaf(mv, (float)a[q], x[idx]);
                out[idx] = val;
                ssum[mi][q] += val;
                ssq[mi][q]  += val * val;
            }
        }
    }
    // Reduce across the 16 lanes (l15) sharing each channel, then atomics.
    #pragma unroll
    for (int mi = 0; mi < 4; mi++) {
        #pragma unroll
        for (int q = 0; q < 4; q++) {
            float s = ssum[mi][q], sq = ssq[mi][q];
            #pragma unroll
            for (int off = 1; off < 16; off <<= 1) {
                s  += __shfl_xor(s, off);
                sq += __shfl_xor(sq, off);
            }
            if (l15 == 0) {
                int co = co_w + mi * 16 + l4 * 4 + q;
                atomicAdd(&wsf[F_SUM + co], s);
                atomicAdd(&wsf[F_SQ  + co], sq);
            }
        }
    }
}

// ---------------------------------------------------------------------------
// BN finalize (per-plane, from fused stats) + normalize + ReLU, in place.
__global__ void epilogue_kernel(float* __restrict__ out,
                                const float* __restrict__ wsf,
                                const float* __restrict__ g,
                                const float* __restrict__ bt) {
    int plane = blockIdx.x;   // b*256 + c
    int c = plane & 255;
    const float n = (float)(Bn * HWn);
    float mean = wsf[F_SUM + c] / n;
    float var  = wsf[F_SQ + c] / n - mean * mean;
    float sc = g[c] * rsqrtf(var + EPSv);
    float sh = bt[c] - mean * sc;
    float4* o4 = (float4*)(out + (size_t)plane * HWn);
    for (int i = threadIdx.x; i < HWn / 4; i += 256) {
        float4 v = o4[i];
        v.x = fmaxf(fmaf(v.x, sc, sh), 0.0f);
        v.y = fmaxf(fmaf(v.y, sc, sh), 0.0f);
        v.z = fmaxf(fmaf(v.z, sc, sh), 0.0f);
        v.w = fmaxf(fmaf(v.w, sc, sh), 0.0f);
        o4[i] = v;
    }
}

// ---------------------------------------------------------------------------
extern "C" void kernel_launch(void* const* d_in, const int* in_sizes, int n_in,
                              void* d_out, int out_size, void* d_ws, size_t ws_size,
                              hipStream_t stream) {
    const float* x     = (const float*)d_in[0];
    const float* w     = (const float*)d_in[1];
    const float* gamma = (const float*)d_in[2];
    const float* beta  = (const float*)d_in[3];
    float* out = (float*)d_out;

    float*   wsf = (float*)d_ws;
    uint8_t* wpk = (uint8_t*)d_ws + WPK_OFF;
    uint8_t* act = (uint8_t*)d_ws + ACT_OFF;

    pack_all<<<dim3(428), dim3(256), 0, stream>>>(x, w, wsf, wpk, act);
    conv_mfma<<<dim3(896), dim3(256), 0, stream>>>(act, wpk, x, wsf, out);
    epilogue_kernel<<<dim3(Bn * Cn), dim3(256), 0, stream>>>(out, wsf, gamma, beta);
}